// Round 15
// baseline (590.402 us; speedup 1.0000x reference)
//
#include <hip/hip_runtime.h>
#include <math.h>

#define N 96
#define PAD 100        // padded LDS row stride (floats)
#define T 768          // 12 waves, one workgroup, one CU
#define ITERS 50
#define LW 52          // neighbor-list width (u16 entries, padded to x4)

typedef float f2 __attribute__((ext_vector_type(2)));
typedef float f4 __attribute__((ext_vector_type(4)));
typedef unsigned short u16x4 __attribute__((ext_vector_type(4)));

// lane-group max via DPP (VALU pipe, no LDS traffic); CTRL must be constexpr
template <int CTRL>
__device__ __forceinline__ float dppmax(float m) {
    int mi = __builtin_bit_cast(int, m);
    int sw = __builtin_amdgcn_update_dpp(mi, mi, CTRL, 0xf, 0xf, true);
    return fmaxf(m, __builtin_bit_cast(float, sw));
}
#define DPP_XOR1 0xB1  // quad_perm:[1,0,3,2]
#define DPP_XOR2 0x4E  // quad_perm:[2,3,0,1]

// Fully fused MPM, one workgroup, 3 barriers/iter.
// M-phase: q=t&3 (b-quarter, 24 b), cq=(t>>2)%24 -> cols 4cq..4cq+3,
//          g=(t>>2)/24 -> rows j≡g (mod 8), 12 rows (fully unrolled, const
//          ds offsets). W[4][12] f2 (96 VGPRs); v_pk_mul products; 4
//          independent max chains per column; 2-stage DPP quad combine;
//          q==0 writes b128. X reads: 72 b128/lane (half of round-14).
// Agg:     ac=t%48 -> cols 2ac,2ac+1 ; rows i = t/48 + 16k (k=0..5);
//          f2 neighbor gathers via byte-offset lists; diag X re-read from
//          Xs (identical bits; frees 12 persistent VGPRs).
__global__ __launch_bounds__(T)
__attribute__((amdgpu_waves_per_eu(3, 3)))
void k_fused(const float* __restrict__ A,
             const float* __restrict__ vec,
             float* __restrict__ out) {
    __shared__ float Xs[N * PAD];            // 38400 B : X (staging B, then A)
    __shared__ float Ms[(N + 1) * PAD];      // 38800 B : full M + zero row 96
    __shared__ unsigned short lst[N * LW];   //  9984 B : nbr BYTE offsets (j*400)
    __shared__ short cnt4[N];                // padded counts (multiple of 4)
    __shared__ float degA[N];
    __shared__ float degB[N];
    __shared__ float red[T / 64];

    const int t = threadIdx.x;
    const int q = t & 3;                   // b-quarter
    const int p = t >> 2;
    const int cq = p % 24;                 // column-quad id (M-phase)
    const int g = p / 24;                  // row group 0..7
    const int ac = t % 48;                 // agg column-pair id
    const int ri = t / 48;                 // agg row base 0..15
    const float s1 = 1.0f / (1.0f + expf(-1.0f));   // sigmoid(1) = diag of B
    const float s1s1 = s1 * s1;

    // ---- setup phase 0: B -> Xs (staging) ----
#pragma unroll
    for (int k = 0; k < 12; ++k) {
        int e = t + k * T;
        int rr = e / N, cc = e % N;
        float logit;
        if (rr == cc) {
            logit = 1.0f;
        } else {
            int i = rr < cc ? rr : cc;
            int j = rr < cc ? cc : rr;
            int idx = i * 95 - (i * (i - 1)) / 2 + (j - i - 1);
            logit = vec[idx];
        }
        Xs[rr * PAD + cc] = 1.0f / (1.0f + expf(-logit));
    }
    __syncthreads();

    // W quarter-columns as f2 pairs (B symmetric: col a == row a), diag=0
    f2 Wp[4][12];
#pragma unroll
    for (int c = 0; c < 4; ++c) {
        int col = 4 * cq + c;
#pragma unroll
        for (int k = 0; k < 12; ++k) {
            int b = 24 * q + 2 * k;
            float w0 = (b == col) ? 0.f : Xs[b * PAD + col] * s1s1;
            float w1 = (b + 1 == col) ? 0.f : Xs[(b + 1) * PAD + col] * s1s1;
            Wp[c][k] = (f2){w0, w1};
        }
    }

    if (t < N) {
        float s = 0.f;
        for (int rr = 0; rr < N; ++rr) s += Xs[rr * PAD + t];
        degB[t] = s;
    }
    __syncthreads();   // all reads of B done

    // ---- setup phase 1: A -> Xs (staging) ----
#pragma unroll
    for (int k = 0; k < 12; ++k) {
        int e = t + k * T;
        Xs[(e / N) * PAD + (e % N)] = A[e];
    }
    __syncthreads();

    if (t < N) {
        float s = 0.f;
        for (int rr = 0; rr < N; ++rr) s += Xs[rr * PAD + t];   // A symmetric
        degA[t] = s;
    } else if (t < 2 * N) {
        int i = t - N;
        int c_ = 0;
        for (int j = 0; j < N; ++j) {
            if (j != i && Xs[j * PAD + i] > 0.5f)                // A symmetric
                lst[i * LW + c_++] = (unsigned short)(j * PAD * 4);
        }
        while (c_ & 3) lst[i * LW + c_++] = (unsigned short)(N * PAD * 4);
        cnt4[i] = (short)c_;
    }
    // zero row 96 of Ms (pad target) — written once, never overwritten
    if (t < PAD) Ms[N * PAD + t] = 0.0f;
    __syncthreads();   // lists/degs ready, Xs(A) reads done

    // node-sim coefficients (agg: 6 rows x 2 cols); diag X stays in LDS
    f2 ns2[6];
#pragma unroll
    for (int k = 0; k < 6; ++k) {
        int i = ri + 16 * k;
        ns2[k] = (f2){s1 / (fabsf(degA[i] - degB[2 * ac]) + 1.0f),
                      s1 / (fabsf(degA[i] - degB[2 * ac + 1]) + 1.0f)};
    }

    // X0 = 1/96 everywhere (||X0|| = 1 exactly)
#pragma unroll
    for (int k = 0; k < 12; ++k) {
        int e = t + k * T;
        Xs[(e / N) * PAD + (e % N)] = (1.0f / 96.0f);
    }
    __syncthreads();

    const float* xbase = &Xs[g * PAD + 24 * q];      // row jj -> + jj*8*PAD
    float* mbase = &Ms[g * PAD + 4 * cq];            // row jj -> + jj*8*PAD
    const char* MsaB = (const char*)Ms + 8 * ac;     // agg col-pair base (bytes)
    const char* XsaB = (const char*)Xs + 8 * ac;     // agg diag base (bytes)

    // ---- main loop ----
    for (int it = 0; it < ITERS; ++it) {
        // M-phase: 12 rows j = 8*jj + g, fully unrolled, const ds offsets
#pragma unroll
        for (int jj = 0; jj < 12; ++jj) {
            const float* xr = xbase + jj * 8 * PAD;
            float4 xv0 = *(const float4*)(xr);
            float4 xv1 = *(const float4*)(xr + 4);
            float4 xv2 = *(const float4*)(xr + 8);
            float4 xv3 = *(const float4*)(xr + 12);
            float4 xv4 = *(const float4*)(xr + 16);
            float4 xv5 = *(const float4*)(xr + 20);
            f2 xp0  = (f2){xv0.x, xv0.y}, xp1  = (f2){xv0.z, xv0.w};
            f2 xp2  = (f2){xv1.x, xv1.y}, xp3  = (f2){xv1.z, xv1.w};
            f2 xp4  = (f2){xv2.x, xv2.y}, xp5  = (f2){xv2.z, xv2.w};
            f2 xp6  = (f2){xv3.x, xv3.y}, xp7  = (f2){xv3.z, xv3.w};
            f2 xp8  = (f2){xv4.x, xv4.y}, xp9  = (f2){xv4.z, xv4.w};
            f2 xp10 = (f2){xv5.x, xv5.y}, xp11 = (f2){xv5.z, xv5.w};

            float mc[4];
#pragma unroll
            for (int c = 0; c < 4; ++c) {
                f2 pp;
                pp = Wp[c][0] * xp0;                 // v_pk_mul_f32
                float c0x = pp.x, c0y = pp.y;
                pp = Wp[c][1] * xp1;
                float c1x = pp.x, c1y = pp.y;
                pp = Wp[c][2]  * xp2;  c0x = fmaxf(c0x, pp.x); c0y = fmaxf(c0y, pp.y);
                pp = Wp[c][3]  * xp3;  c1x = fmaxf(c1x, pp.x); c1y = fmaxf(c1y, pp.y);
                pp = Wp[c][4]  * xp4;  c0x = fmaxf(c0x, pp.x); c0y = fmaxf(c0y, pp.y);
                pp = Wp[c][5]  * xp5;  c1x = fmaxf(c1x, pp.x); c1y = fmaxf(c1y, pp.y);
                pp = Wp[c][6]  * xp6;  c0x = fmaxf(c0x, pp.x); c0y = fmaxf(c0y, pp.y);
                pp = Wp[c][7]  * xp7;  c1x = fmaxf(c1x, pp.x); c1y = fmaxf(c1y, pp.y);
                pp = Wp[c][8]  * xp8;  c0x = fmaxf(c0x, pp.x); c0y = fmaxf(c0y, pp.y);
                pp = Wp[c][9]  * xp9;  c1x = fmaxf(c1x, pp.x); c1y = fmaxf(c1y, pp.y);
                pp = Wp[c][10] * xp10; c0x = fmaxf(c0x, pp.x); c0y = fmaxf(c0y, pp.y);
                pp = Wp[c][11] * xp11; c1x = fmaxf(c1x, pp.x); c1y = fmaxf(c1y, pp.y);
                float m = fmaxf(fmaxf(c0x, c0y), fmaxf(c1x, c1y));
                // combine b-quarters across the lane quad (exact, VALU pipe)
                m = dppmax<DPP_XOR1>(m);
                m = dppmax<DPP_XOR2>(m);
                mc[c] = m;
            }
            if (q == 0)
                *(f4*)(mbase + jj * 8 * PAD) = (f4){mc[0], mc[1], mc[2], mc[3]};
        }
        __syncthreads();   // (A) Ms complete; all Xs reads done

        // aggregate (diag from Xs, then ascending-j neighbors — exact order)
        f2 y2[6];
#pragma unroll
        for (int k = 0; k < 6; ++k) {
            int i = ri + 16 * k;
            f2 xd = *(const f2*)(XsaB + i * PAD * 4);
            f2 acc = xd * ns2[k];
            int nch = (int)cnt4[i] >> 2;
            const unsigned short* lp = &lst[i * LW];
            for (int cc = 0; cc < nch; ++cc) {
                u16x4 o = *(const u16x4*)(lp + 4 * cc);
                acc += *(const f2*)(MsaB + o.x);
                acc += *(const f2*)(MsaB + o.y);
                acc += *(const f2*)(MsaB + o.z);
                acc += *(const f2*)(MsaB + o.w);
            }
            y2[k] = acc;
        }

        // block-wide norm (deterministic fixed tree)
        float ss = 0.f;
#pragma unroll
        for (int k = 0; k < 6; ++k) {
            ss = fmaf(y2[k].x, y2[k].x, ss);
            ss = fmaf(y2[k].y, y2[k].y, ss);
        }
#pragma unroll
        for (int mm = 1; mm < 64; mm <<= 1) ss += __shfl_xor(ss, mm, 64);
        if ((t & 63) == 0) red[t >> 6] = ss;
        __syncthreads();   // (B) red ready; all Ms/Xs-diag reads done
        float s = 0.f;
#pragma unroll
        for (int w2 = 0; w2 < T / 64; ++w2) s += red[w2];
        float inv = 1.0f / sqrtf(s);
        f2 inv2 = (f2){inv, inv};
#pragma unroll
        for (int k = 0; k < 6; ++k) {
            int i = ri + 16 * k;
            f2 xn = y2[k] * inv2;
            *(f2*)&Xs[i * PAD + 2 * ac] = xn;
        }
        __syncthreads();   // (C) Xs ready for next iter; Ms safe to overwrite
    }

    // ---- output ----
#pragma unroll
    for (int k = 0; k < 12; ++k) {
        int e = t + k * T;
        out[e] = Xs[(e / N) * PAD + (e % N)];
    }
}

extern "C" void kernel_launch(void* const* d_in, const int* in_sizes, int n_in,
                              void* d_out, int out_size, void* d_ws, size_t ws_size,
                              hipStream_t stream) {
    const float* A = (const float*)d_in[0];     // A_gt, 96*96
    const float* vec = (const float*)d_in[1];   // vec_logits, 4560
    float* out = (float*)d_out;
    k_fused<<<1, T, 0, stream>>>(A, vec, out);
}

// Round 16
// 560.921 us; speedup vs baseline: 1.0526x; 1.0526x over previous
//
#include <hip/hip_runtime.h>
#include <math.h>

#define N 96
#define PAD 100        // padded LDS row stride (floats)
#define T 768          // 12 waves, one workgroup, one CU
#define ITERS 50
#define NORM_EVERY 10  // normalize on it%10==9 (incl. final it=49); f is
                       // degree-1 homogeneous so deferred norm is exact up
                       // to rounding; growth <= 7.2^10 ~ 4e8, f32-safe
#define LW 52          // neighbor-list width (u16 entries, padded to x4)

typedef float f2 __attribute__((ext_vector_type(2)));
typedef unsigned short u16x4 __attribute__((ext_vector_type(4)));

// lane-group max via DPP (VALU pipe, no LDS traffic); CTRL must be constexpr
template <int CTRL>
__device__ __forceinline__ float dppmax(float m) {
    int mi = __builtin_bit_cast(int, m);
    int sw = __builtin_amdgcn_update_dpp(mi, mi, CTRL, 0xf, 0xf, true);
    return fmaxf(m, __builtin_bit_cast(float, sw));
}
#define DPP_XOR1 0xB1  // quad_perm:[1,0,3,2]
#define DPP_XOR2 0x4E  // quad_perm:[2,3,0,1]

// Fully fused MPM, one workgroup (round-14 structure + deferred norm).
// M-phase: t=(p<<2)|q : q=b-quarter (24 b), ap=p%48 -> cols a0=2ap,a0+1,
//          g=p/48 -> rows j≡g (mod 4), 24 rows (fully unrolled, const ds
//          offsets). W as f2 pairs (48 VGPRs); v_pk_mul products; 4
//          independent max chains per column; DPP quad combine.
// Agg:     ac=t%48 -> cols 2ac,2ac+1 ; rows i = t/48 + 16k (k=0..5);
//          f2 neighbor gathers via byte-offset lists; diag X in regs.
// Norm:    only on it%NORM_EVERY==NORM_EVERY-1 (3 barriers); else 2 barriers.
__global__ __launch_bounds__(T)
__attribute__((amdgpu_waves_per_eu(3, 3)))
void k_fused(const float* __restrict__ A,
             const float* __restrict__ vec,
             float* __restrict__ out) {
    __shared__ float Xs[N * PAD];            // 38400 B : X (staging B, then A)
    __shared__ float Ms[(N + 1) * PAD];      // 38800 B : full M + zero row 96
    __shared__ unsigned short lst[N * LW];   //  9984 B : nbr BYTE offsets (j*400)
    __shared__ short cnt4[N];                // padded counts (multiple of 4)
    __shared__ float degA[N];
    __shared__ float degB[N];
    __shared__ float red[T / 64];

    const int t = threadIdx.x;
    const int q = t & 3;                   // b-quarter
    const int p = t >> 2;
    const int ap = p % 48;                 // column-pair id (M-phase)
    const int g = p / 48;                  // row group 0..3
    const int a0 = 2 * ap;
    const int ac = t % 48;                 // agg column-pair id
    const int ri = t / 48;                 // agg row base 0..15
    const float s1 = 1.0f / (1.0f + expf(-1.0f));   // sigmoid(1) = diag of B
    const float s1s1 = s1 * s1;

    // ---- setup phase 0: B -> Xs (staging) ----
#pragma unroll
    for (int k = 0; k < 12; ++k) {
        int e = t + k * T;
        int rr = e / N, cc = e % N;
        float logit;
        if (rr == cc) {
            logit = 1.0f;
        } else {
            int i = rr < cc ? rr : cc;
            int j = rr < cc ? cc : rr;
            int idx = i * 95 - (i * (i - 1)) / 2 + (j - i - 1);
            logit = vec[idx];
        }
        Xs[rr * PAD + cc] = 1.0f / (1.0f + expf(-logit));
    }
    __syncthreads();

    // W quarter-columns as f2 pairs (B symmetric: col a == row a), diag=0
    f2 Wp0[12], Wp1[12];
#pragma unroll
    for (int k = 0; k < 12; ++k) {
        int b = 24 * q + 2 * k;
        float w00 = Xs[b * PAD + a0] * s1s1;
        float w01 = Xs[(b + 1) * PAD + a0] * s1s1;
        float w10 = Xs[b * PAD + a0 + 1] * s1s1;
        float w11 = Xs[(b + 1) * PAD + a0 + 1] * s1s1;
        if (b == a0) w00 = 0.0f;
        if (b + 1 == a0) w01 = 0.0f;
        if (b == a0 + 1) w10 = 0.0f;
        if (b + 1 == a0 + 1) w11 = 0.0f;
        Wp0[k] = (f2){w00, w01};
        Wp1[k] = (f2){w10, w11};
    }

    if (t < N) {
        float s = 0.f;
        for (int rr = 0; rr < N; ++rr) s += Xs[rr * PAD + t];
        degB[t] = s;
    }
    __syncthreads();   // all reads of B done

    // ---- setup phase 1: A -> Xs (staging) ----
#pragma unroll
    for (int k = 0; k < 12; ++k) {
        int e = t + k * T;
        Xs[(e / N) * PAD + (e % N)] = A[e];
    }
    __syncthreads();

    if (t < N) {
        float s = 0.f;
        for (int rr = 0; rr < N; ++rr) s += Xs[rr * PAD + t];   // A symmetric
        degA[t] = s;
    } else if (t < 2 * N) {
        int i = t - N;
        int c_ = 0;
        for (int j = 0; j < N; ++j) {
            if (j != i && Xs[j * PAD + i] > 0.5f)                // A symmetric
                lst[i * LW + c_++] = (unsigned short)(j * PAD * 4);
        }
        while (c_ & 3) lst[i * LW + c_++] = (unsigned short)(N * PAD * 4);
        cnt4[i] = (short)c_;
    }
    // zero row 96 of Ms (pad target) — written once, never overwritten
    if (t < PAD) Ms[N * PAD + t] = 0.0f;
    __syncthreads();   // lists/degs ready, Xs(A) reads done

    // node-sim coefficients + register-resident diag X (agg: 6 rows x 2 cols)
    f2 ns2[6], x2[6];
#pragma unroll
    for (int k = 0; k < 6; ++k) {
        int i = ri + 16 * k;
        ns2[k] = (f2){s1 / (fabsf(degA[i] - degB[2 * ac]) + 1.0f),
                      s1 / (fabsf(degA[i] - degB[2 * ac + 1]) + 1.0f)};
        x2[k] = (f2){1.0f / 96.0f, 1.0f / 96.0f};
    }

    // X0 = 1/96 everywhere (||X0|| = 1 exactly)
#pragma unroll
    for (int k = 0; k < 12; ++k) {
        int e = t + k * T;
        Xs[(e / N) * PAD + (e % N)] = (1.0f / 96.0f);
    }
    __syncthreads();

    const float* xbase = &Xs[g * PAD + 24 * q];      // row jj -> + jj*4*PAD
    float* mbase = &Ms[g * PAD + a0];                // row jj -> + jj*4*PAD
    const char* MsaB = (const char*)Ms + 8 * ac;     // agg col-pair base (bytes)

    // ---- main loop ----
    for (int it = 0; it < ITERS; ++it) {
        // M-phase: 24 rows j = 4*jj + g, fully unrolled, const ds offsets
#pragma unroll
        for (int jj = 0; jj < 24; ++jj) {
            const float* xr = xbase + jj * 4 * PAD;
            float4 xv0 = *(const float4*)(xr);
            float4 xv1 = *(const float4*)(xr + 4);
            float4 xv2 = *(const float4*)(xr + 8);
            float4 xv3 = *(const float4*)(xr + 12);
            float4 xv4 = *(const float4*)(xr + 16);
            float4 xv5 = *(const float4*)(xr + 20);
            f2 xp0  = (f2){xv0.x, xv0.y}, xp1  = (f2){xv0.z, xv0.w};
            f2 xp2  = (f2){xv1.x, xv1.y}, xp3  = (f2){xv1.z, xv1.w};
            f2 xp4  = (f2){xv2.x, xv2.y}, xp5  = (f2){xv2.z, xv2.w};
            f2 xp6  = (f2){xv3.x, xv3.y}, xp7  = (f2){xv3.z, xv3.w};
            f2 xp8  = (f2){xv4.x, xv4.y}, xp9  = (f2){xv4.z, xv4.w};
            f2 xp10 = (f2){xv5.x, xv5.y}, xp11 = (f2){xv5.z, xv5.w};

            // col a0: 4 independent chains (even-k / odd-k, x / y)
            f2 pp;
            pp = Wp0[0] * xp0;                    // v_pk_mul_f32
            float c0x = pp.x, c0y = pp.y;
            pp = Wp0[1] * xp1;
            float c1x = pp.x, c1y = pp.y;
            pp = Wp0[2]  * xp2;  c0x = fmaxf(c0x, pp.x); c0y = fmaxf(c0y, pp.y);
            pp = Wp0[3]  * xp3;  c1x = fmaxf(c1x, pp.x); c1y = fmaxf(c1y, pp.y);
            pp = Wp0[4]  * xp4;  c0x = fmaxf(c0x, pp.x); c0y = fmaxf(c0y, pp.y);
            pp = Wp0[5]  * xp5;  c1x = fmaxf(c1x, pp.x); c1y = fmaxf(c1y, pp.y);
            pp = Wp0[6]  * xp6;  c0x = fmaxf(c0x, pp.x); c0y = fmaxf(c0y, pp.y);
            pp = Wp0[7]  * xp7;  c1x = fmaxf(c1x, pp.x); c1y = fmaxf(c1y, pp.y);
            pp = Wp0[8]  * xp8;  c0x = fmaxf(c0x, pp.x); c0y = fmaxf(c0y, pp.y);
            pp = Wp0[9]  * xp9;  c1x = fmaxf(c1x, pp.x); c1y = fmaxf(c1y, pp.y);
            pp = Wp0[10] * xp10; c0x = fmaxf(c0x, pp.x); c0y = fmaxf(c0y, pp.y);
            pp = Wp0[11] * xp11; c1x = fmaxf(c1x, pp.x); c1y = fmaxf(c1y, pp.y);
            float m0 = fmaxf(fmaxf(c0x, c0y), fmaxf(c1x, c1y));

            // col a0+1
            pp = Wp1[0] * xp0;
            float d0x = pp.x, d0y = pp.y;
            pp = Wp1[1] * xp1;
            float d1x = pp.x, d1y = pp.y;
            pp = Wp1[2]  * xp2;  d0x = fmaxf(d0x, pp.x); d0y = fmaxf(d0y, pp.y);
            pp = Wp1[3]  * xp3;  d1x = fmaxf(d1x, pp.x); d1y = fmaxf(d1y, pp.y);
            pp = Wp1[4]  * xp4;  d0x = fmaxf(d0x, pp.x); d0y = fmaxf(d0y, pp.y);
            pp = Wp1[5]  * xp5;  d1x = fmaxf(d1x, pp.x); d1y = fmaxf(d1y, pp.y);
            pp = Wp1[6]  * xp6;  d0x = fmaxf(d0x, pp.x); d0y = fmaxf(d0y, pp.y);
            pp = Wp1[7]  * xp7;  d1x = fmaxf(d1x, pp.x); d1y = fmaxf(d1y, pp.y);
            pp = Wp1[8]  * xp8;  d0x = fmaxf(d0x, pp.x); d0y = fmaxf(d0y, pp.y);
            pp = Wp1[9]  * xp9;  d1x = fmaxf(d1x, pp.x); d1y = fmaxf(d1y, pp.y);
            pp = Wp1[10] * xp10; d0x = fmaxf(d0x, pp.x); d0y = fmaxf(d0y, pp.y);
            pp = Wp1[11] * xp11; d1x = fmaxf(d1x, pp.x); d1y = fmaxf(d1y, pp.y);
            float m1 = fmaxf(fmaxf(d0x, d0y), fmaxf(d1x, d1y));

            // combine b-quarters across the lane quad (exact, VALU pipe)
            m0 = dppmax<DPP_XOR1>(m0);
            m0 = dppmax<DPP_XOR2>(m0);
            m1 = dppmax<DPP_XOR1>(m1);
            m1 = dppmax<DPP_XOR2>(m1);
            if (q == 0)
                *(f2*)(mbase + jj * 4 * PAD) = (f2){m0, m1};
        }
        __syncthreads();   // (A) Ms complete; all Xs reads done

        // aggregate (diag from regs, then ascending-j neighbors — exact order)
        f2 y2[6];
#pragma unroll
        for (int k = 0; k < 6; ++k) {
            int i = ri + 16 * k;
            f2 acc = x2[k] * ns2[k];
            int nch = (int)cnt4[i] >> 2;
            const unsigned short* lp = &lst[i * LW];
            for (int cc = 0; cc < nch; ++cc) {
                u16x4 o = *(const u16x4*)(lp + 4 * cc);
                acc += *(const f2*)(MsaB + o.x);
                acc += *(const f2*)(MsaB + o.y);
                acc += *(const f2*)(MsaB + o.z);
                acc += *(const f2*)(MsaB + o.w);
            }
            y2[k] = acc;
        }

        if ((it % NORM_EVERY) == NORM_EVERY - 1) {
            // block-wide norm (deterministic fixed tree); exact scale point
            float ss = 0.f;
#pragma unroll
            for (int k = 0; k < 6; ++k) {
                ss = fmaf(y2[k].x, y2[k].x, ss);
                ss = fmaf(y2[k].y, y2[k].y, ss);
            }
#pragma unroll
            for (int mm = 1; mm < 64; mm <<= 1) ss += __shfl_xor(ss, mm, 64);
            if ((t & 63) == 0) red[t >> 6] = ss;
            __syncthreads();   // (B) red ready; all Ms reads done
            float s = 0.f;
#pragma unroll
            for (int w2 = 0; w2 < T / 64; ++w2) s += red[w2];
            float inv = 1.0f / sqrtf(s);
            f2 inv2 = (f2){inv, inv};
#pragma unroll
            for (int k = 0; k < 6; ++k) {
                f2 xn = y2[k] * inv2;
                x2[k] = xn;
                *(f2*)&Xs[(ri + 16 * k) * PAD + 2 * ac] = xn;
            }
        } else {
            // deferred norm: write unnormalized (homogeneous iteration)
#pragma unroll
            for (int k = 0; k < 6; ++k) {
                x2[k] = y2[k];
                *(f2*)&Xs[(ri + 16 * k) * PAD + 2 * ac] = y2[k];
            }
        }
        __syncthreads();   // (C) Xs ready for next iter; Ms safe to overwrite
    }

    // ---- output (final iter was a norm iter: X is normalized) ----
#pragma unroll
    for (int k = 0; k < 12; ++k) {
        int e = t + k * T;
        out[e] = Xs[(e / N) * PAD + (e % N)];
    }
}

extern "C" void kernel_launch(void* const* d_in, const int* in_sizes, int n_in,
                              void* d_out, int out_size, void* d_ws, size_t ws_size,
                              hipStream_t stream) {
    const float* A = (const float*)d_in[0];     // A_gt, 96*96
    const float* vec = (const float*)d_in[1];   // vec_logits, 4560
    float* out = (float*)d_out;
    k_fused<<<1, T, 0, stream>>>(A, vec, out);
}

// Round 17
// 516.580 us; speedup vs baseline: 1.1429x; 1.0858x over previous
//
#include <hip/hip_runtime.h>
#include <math.h>

#define N 96
#define PAD 100        // padded LDS row stride (floats)
#define T 768          // 12 waves, one workgroup, one CU
#define ITERS 50
#define NORM_EVERY 10  // normalize on it%10==9 (incl. final it=49); f is
                       // degree-1 homogeneous so deferred norm is exact up
                       // to rounding; growth f32-safe
#define LW 52          // neighbor-list width (u16 entries, padded to x4)

typedef float f2 __attribute__((ext_vector_type(2)));
typedef unsigned int u32;
typedef u32 u2 __attribute__((ext_vector_type(2)));
typedef unsigned short u16x4 __attribute__((ext_vector_type(4)));

// u32 max == float max for non-negative IEEE floats (all products here >= 0).
// Integer max chains fuse to v_max3_u32 (no NaN-semantics blocker).
__device__ __forceinline__ u32 um(u32 a, u32 b) { return a > b ? a : b; }

// lane-group max via DPP on u32 (VALU pipe); CTRL must be constexpr
template <int CTRL>
__device__ __forceinline__ u32 dppumax(u32 m) {
    int sw = __builtin_amdgcn_update_dpp((int)m, (int)m, CTRL, 0xf, 0xf, true);
    return um(m, (u32)sw);
}
#define DPP_XOR1 0xB1  // quad_perm:[1,0,3,2]
#define DPP_XOR2 0x4E  // quad_perm:[2,3,0,1]

// Fully fused MPM, one workgroup (round-16 structure + u32-max3 M-phase).
// M-phase: t=(p<<2)|q : q=b-quarter (24 b), ap=p%48 -> cols a0=2ap,a0+1,
//          g=p/48 -> rows j≡g (mod 4), 24 rows (fully unrolled, const ds
//          offsets). W as f2 pairs (48 VGPRs); v_pk_mul products; per col
//          2 u32-max chains (depth 6, v_max3_u32); DPP quad combine.
// Agg:     ac=t%48 -> cols 2ac,2ac+1 ; rows i = t/48 + 16k (k=0..5);
//          f2 neighbor gathers via byte-offset lists; diag X in regs.
// Norm:    only on it%NORM_EVERY==NORM_EVERY-1 (3 barriers); else 2 barriers.
__global__ __launch_bounds__(T)
__attribute__((amdgpu_waves_per_eu(3, 3)))
void k_fused(const float* __restrict__ A,
             const float* __restrict__ vec,
             float* __restrict__ out) {
    __shared__ float Xs[N * PAD];            // 38400 B : X (staging B, then A)
    __shared__ float Ms[(N + 1) * PAD];      // 38800 B : full M + zero row 96
    __shared__ unsigned short lst[N * LW];   //  9984 B : nbr BYTE offsets (j*400)
    __shared__ short cnt4[N];                // padded counts (multiple of 4)
    __shared__ float degA[N];
    __shared__ float degB[N];
    __shared__ float red[T / 64];

    const int t = threadIdx.x;
    const int q = t & 3;                   // b-quarter
    const int p = t >> 2;
    const int ap = p % 48;                 // column-pair id (M-phase)
    const int g = p / 48;                  // row group 0..3
    const int a0 = 2 * ap;
    const int ac = t % 48;                 // agg column-pair id
    const int ri = t / 48;                 // agg row base 0..15
    const float s1 = 1.0f / (1.0f + expf(-1.0f));   // sigmoid(1) = diag of B
    const float s1s1 = s1 * s1;

    // ---- setup phase 0: B -> Xs (staging) ----
#pragma unroll
    for (int k = 0; k < 12; ++k) {
        int e = t + k * T;
        int rr = e / N, cc = e % N;
        float logit;
        if (rr == cc) {
            logit = 1.0f;
        } else {
            int i = rr < cc ? rr : cc;
            int j = rr < cc ? cc : rr;
            int idx = i * 95 - (i * (i - 1)) / 2 + (j - i - 1);
            logit = vec[idx];
        }
        Xs[rr * PAD + cc] = 1.0f / (1.0f + expf(-logit));
    }
    __syncthreads();

    // W quarter-columns as f2 pairs (B symmetric: col a == row a), diag=0
    f2 Wp0[12], Wp1[12];
#pragma unroll
    for (int k = 0; k < 12; ++k) {
        int b = 24 * q + 2 * k;
        float w00 = Xs[b * PAD + a0] * s1s1;
        float w01 = Xs[(b + 1) * PAD + a0] * s1s1;
        float w10 = Xs[b * PAD + a0 + 1] * s1s1;
        float w11 = Xs[(b + 1) * PAD + a0 + 1] * s1s1;
        if (b == a0) w00 = 0.0f;
        if (b + 1 == a0) w01 = 0.0f;
        if (b == a0 + 1) w10 = 0.0f;
        if (b + 1 == a0 + 1) w11 = 0.0f;
        Wp0[k] = (f2){w00, w01};
        Wp1[k] = (f2){w10, w11};
    }

    if (t < N) {
        float s = 0.f;
        for (int rr = 0; rr < N; ++rr) s += Xs[rr * PAD + t];
        degB[t] = s;
    }
    __syncthreads();   // all reads of B done

    // ---- setup phase 1: A -> Xs (staging) ----
#pragma unroll
    for (int k = 0; k < 12; ++k) {
        int e = t + k * T;
        Xs[(e / N) * PAD + (e % N)] = A[e];
    }
    __syncthreads();

    if (t < N) {
        float s = 0.f;
        for (int rr = 0; rr < N; ++rr) s += Xs[rr * PAD + t];   // A symmetric
        degA[t] = s;
    } else if (t < 2 * N) {
        int i = t - N;
        int c_ = 0;
        for (int j = 0; j < N; ++j) {
            if (j != i && Xs[j * PAD + i] > 0.5f)                // A symmetric
                lst[i * LW + c_++] = (unsigned short)(j * PAD * 4);
        }
        while (c_ & 3) lst[i * LW + c_++] = (unsigned short)(N * PAD * 4);
        cnt4[i] = (short)c_;
    }
    // zero row 96 of Ms (pad target) — written once, never overwritten
    if (t < PAD) Ms[N * PAD + t] = 0.0f;
    __syncthreads();   // lists/degs ready, Xs(A) reads done

    // node-sim coefficients + register-resident diag X (agg: 6 rows x 2 cols)
    f2 ns2[6], x2[6];
#pragma unroll
    for (int k = 0; k < 6; ++k) {
        int i = ri + 16 * k;
        ns2[k] = (f2){s1 / (fabsf(degA[i] - degB[2 * ac]) + 1.0f),
                      s1 / (fabsf(degA[i] - degB[2 * ac + 1]) + 1.0f)};
        x2[k] = (f2){1.0f / 96.0f, 1.0f / 96.0f};
    }

    // X0 = 1/96 everywhere (||X0|| = 1 exactly)
#pragma unroll
    for (int k = 0; k < 12; ++k) {
        int e = t + k * T;
        Xs[(e / N) * PAD + (e % N)] = (1.0f / 96.0f);
    }
    __syncthreads();

    const float* xbase = &Xs[g * PAD + 24 * q];      // row jj -> + jj*4*PAD
    float* mbase = &Ms[g * PAD + a0];                // row jj -> + jj*4*PAD
    const char* MsaB = (const char*)Ms + 8 * ac;     // agg col-pair base (bytes)

    // ---- main loop ----
    for (int it = 0; it < ITERS; ++it) {
        // M-phase: 24 rows j = 4*jj + g, fully unrolled, const ds offsets
#pragma unroll
        for (int jj = 0; jj < 24; ++jj) {
            const float* xr = xbase + jj * 4 * PAD;
            float4 xv0 = *(const float4*)(xr);
            float4 xv1 = *(const float4*)(xr + 4);
            float4 xv2 = *(const float4*)(xr + 8);
            float4 xv3 = *(const float4*)(xr + 12);
            float4 xv4 = *(const float4*)(xr + 16);
            float4 xv5 = *(const float4*)(xr + 20);
            f2 xp0  = (f2){xv0.x, xv0.y}, xp1  = (f2){xv0.z, xv0.w};
            f2 xp2  = (f2){xv1.x, xv1.y}, xp3  = (f2){xv1.z, xv1.w};
            f2 xp4  = (f2){xv2.x, xv2.y}, xp5  = (f2){xv2.z, xv2.w};
            f2 xp6  = (f2){xv3.x, xv3.y}, xp7  = (f2){xv3.z, xv3.w};
            f2 xp8  = (f2){xv4.x, xv4.y}, xp9  = (f2){xv4.z, xv4.w};
            f2 xp10 = (f2){xv5.x, xv5.y}, xp11 = (f2){xv5.z, xv5.w};

            u2 u;
            // col a0: 2 chains (even-k / odd-k), v_pk_mul + v_max3_u32
            u = __builtin_bit_cast(u2, Wp0[0] * xp0);
            u32 e0 = um(u.x, u.y);
            u = __builtin_bit_cast(u2, Wp0[1] * xp1);
            u32 o0 = um(u.x, u.y);
            u = __builtin_bit_cast(u2, Wp0[2]  * xp2);  e0 = um(um(e0, u.x), u.y);
            u = __builtin_bit_cast(u2, Wp0[3]  * xp3);  o0 = um(um(o0, u.x), u.y);
            u = __builtin_bit_cast(u2, Wp0[4]  * xp4);  e0 = um(um(e0, u.x), u.y);
            u = __builtin_bit_cast(u2, Wp0[5]  * xp5);  o0 = um(um(o0, u.x), u.y);
            u = __builtin_bit_cast(u2, Wp0[6]  * xp6);  e0 = um(um(e0, u.x), u.y);
            u = __builtin_bit_cast(u2, Wp0[7]  * xp7);  o0 = um(um(o0, u.x), u.y);
            u = __builtin_bit_cast(u2, Wp0[8]  * xp8);  e0 = um(um(e0, u.x), u.y);
            u = __builtin_bit_cast(u2, Wp0[9]  * xp9);  o0 = um(um(o0, u.x), u.y);
            u = __builtin_bit_cast(u2, Wp0[10] * xp10); e0 = um(um(e0, u.x), u.y);
            u = __builtin_bit_cast(u2, Wp0[11] * xp11); o0 = um(um(o0, u.x), u.y);
            u32 m0 = um(e0, o0);

            // col a0+1
            u = __builtin_bit_cast(u2, Wp1[0] * xp0);
            u32 e1 = um(u.x, u.y);
            u = __builtin_bit_cast(u2, Wp1[1] * xp1);
            u32 o1 = um(u.x, u.y);
            u = __builtin_bit_cast(u2, Wp1[2]  * xp2);  e1 = um(um(e1, u.x), u.y);
            u = __builtin_bit_cast(u2, Wp1[3]  * xp3);  o1 = um(um(o1, u.x), u.y);
            u = __builtin_bit_cast(u2, Wp1[4]  * xp4);  e1 = um(um(e1, u.x), u.y);
            u = __builtin_bit_cast(u2, Wp1[5]  * xp5);  o1 = um(um(o1, u.x), u.y);
            u = __builtin_bit_cast(u2, Wp1[6]  * xp6);  e1 = um(um(e1, u.x), u.y);
            u = __builtin_bit_cast(u2, Wp1[7]  * xp7);  o1 = um(um(o1, u.x), u.y);
            u = __builtin_bit_cast(u2, Wp1[8]  * xp8);  e1 = um(um(e1, u.x), u.y);
            u = __builtin_bit_cast(u2, Wp1[9]  * xp9);  o1 = um(um(o1, u.x), u.y);
            u = __builtin_bit_cast(u2, Wp1[10] * xp10); e1 = um(um(e1, u.x), u.y);
            u = __builtin_bit_cast(u2, Wp1[11] * xp11); o1 = um(um(o1, u.x), u.y);
            u32 m1 = um(e1, o1);

            // combine b-quarters across the lane quad (exact, VALU pipe)
            m0 = dppumax<DPP_XOR1>(m0);
            m0 = dppumax<DPP_XOR2>(m0);
            m1 = dppumax<DPP_XOR1>(m1);
            m1 = dppumax<DPP_XOR2>(m1);
            if (q == 0)
                *(u2*)(mbase + jj * 4 * PAD) = (u2){m0, m1};
        }
        __syncthreads();   // (A) Ms complete; all Xs reads done

        // aggregate (diag from regs, then ascending-j neighbors — exact order)
        f2 y2[6];
#pragma unroll
        for (int k = 0; k < 6; ++k) {
            int i = ri + 16 * k;
            f2 acc = x2[k] * ns2[k];
            int nch = (int)cnt4[i] >> 2;
            const unsigned short* lp = &lst[i * LW];
            for (int cc = 0; cc < nch; ++cc) {
                u16x4 o = *(const u16x4*)(lp + 4 * cc);
                acc += *(const f2*)(MsaB + o.x);
                acc += *(const f2*)(MsaB + o.y);
                acc += *(const f2*)(MsaB + o.z);
                acc += *(const f2*)(MsaB + o.w);
            }
            y2[k] = acc;
        }

        if ((it % NORM_EVERY) == NORM_EVERY - 1) {
            // block-wide norm (deterministic fixed tree); exact scale point
            float ss = 0.f;
#pragma unroll
            for (int k = 0; k < 6; ++k) {
                ss = fmaf(y2[k].x, y2[k].x, ss);
                ss = fmaf(y2[k].y, y2[k].y, ss);
            }
#pragma unroll
            for (int mm = 1; mm < 64; mm <<= 1) ss += __shfl_xor(ss, mm, 64);
            if ((t & 63) == 0) red[t >> 6] = ss;
            __syncthreads();   // (B) red ready; all Ms reads done
            float s = 0.f;
#pragma unroll
            for (int w2 = 0; w2 < T / 64; ++w2) s += red[w2];
            float inv = 1.0f / sqrtf(s);
            f2 inv2 = (f2){inv, inv};
#pragma unroll
            for (int k = 0; k < 6; ++k) {
                f2 xn = y2[k] * inv2;
                x2[k] = xn;
                *(f2*)&Xs[(ri + 16 * k) * PAD + 2 * ac] = xn;
            }
        } else {
            // deferred norm: write unnormalized (homogeneous iteration)
#pragma unroll
            for (int k = 0; k < 6; ++k) {
                x2[k] = y2[k];
                *(f2*)&Xs[(ri + 16 * k) * PAD + 2 * ac] = y2[k];
            }
        }
        __syncthreads();   // (C) Xs ready for next iter; Ms safe to overwrite
    }

    // ---- output (final iter was a norm iter: X is normalized) ----
#pragma unroll
    for (int k = 0; k < 12; ++k) {
        int e = t + k * T;
        out[e] = Xs[(e / N) * PAD + (e % N)];
    }
}

extern "C" void kernel_launch(void* const* d_in, const int* in_sizes, int n_in,
                              void* d_out, int out_size, void* d_ws, size_t ws_size,
                              hipStream_t stream) {
    const float* A = (const float*)d_in[0];     // A_gt, 96*96
    const float* vec = (const float*)d_in[1];   // vec_logits, 4560
    float* out = (float*)d_out;
    k_fused<<<1, T, 0, stream>>>(A, vec, out);
}